// Round 1
// baseline (8013.108 us; speedup 1.0000x reference)
//
#include <hip/hip_runtime.h>

#define Vv 32000
#define Ee 256
#define Hh 512
#define Ll 128
#define Bb 16
#define Tt 128
#define G3 1536   // 3*H

// ---------------- zero helper ----------------
__global__ void k_zero(float* __restrict__ p, int n) {
  int i = blockIdx.x * 256 + threadIdx.x;
  if (i < n) p[i] = 0.f;
}

// zero outputs[:, 0, :]
__global__ void k_zero_first(float* __restrict__ out) {
  int idx = blockIdx.x * 256 + threadIdx.x;
  if (idx < Bb * Vv) {
    int b = idx / Vv, v = idx % Vv;
    out[(size_t)b * Tt * Vv + v] = 0.f;
  }
}

// ---------------- transpose: in [R][C] -> out [C][R] ----------------
__global__ void k_transpose(const float* __restrict__ in, float* __restrict__ out,
                            int R, int C) {
  __shared__ float tile[32][33];
  int c = blockIdx.x * 32 + threadIdx.x;
  int r0 = blockIdx.y * 32;
  for (int i = threadIdx.y; i < 32; i += 8)
    tile[i][threadIdx.x] = in[(size_t)(r0 + i) * C + c];
  __syncthreads();
  int r = r0 + threadIdx.x;
  int c0 = blockIdx.x * 32;
  for (int i = threadIdx.y; i < 32; i += 8)
    out[(size_t)(c0 + i) * R + r] = tile[threadIdx.x][i];
}

// ---------------- gx = emb[x] @ W_ih^T + b_ih ----------------
// gx[m][g], m = t*16+b (time-major).  WihT is [Ee][G3].
__global__ void k_gx(const int* __restrict__ x, const float* __restrict__ emb,
                     const float* __restrict__ WihT, const float* __restrict__ b_ih,
                     float* __restrict__ gx) {
  int g = blockIdx.y * 256 + threadIdx.x;
  int mt = blockIdx.x;
  __shared__ float A[16][Ee];
  for (int i = 0; i < 16; i++) {
    int m = mt * 16 + i;
    int t = m >> 4, b = m & 15;
    int tok = x[b * Tt + t];
    A[i][threadIdx.x] = emb[(size_t)tok * Ee + threadIdx.x];
  }
  __syncthreads();
  float acc[16];
  float bg = b_ih[g];
#pragma unroll
  for (int i = 0; i < 16; i++) acc[i] = bg;
#pragma unroll 4
  for (int e = 0; e < Ee; e++) {
    float w = WihT[(size_t)e * G3 + g];
#pragma unroll
    for (int i = 0; i < 16; i++) acc[i] = fmaf(A[i][e], w, acc[i]);
  }
#pragma unroll
  for (int i = 0; i < 16; i++)
    gx[(size_t)(mt * 16 + i) * G3 + g] = acc[i];
}

// ---------------- one GRU step ----------------
// grid (2, 16): blockIdx.y = b, blockIdx.x = j-half; 256 threads
// WhhT is [Hh][G3] (transposed), gates in (r, z, n) order.
__global__ void k_gru_step(const float* __restrict__ gx_t, const float* __restrict__ h_in,
                           float* __restrict__ h_out, float* __restrict__ hseq_out,
                           const float* __restrict__ WhhT, const float* __restrict__ b_hh) {
  int b = blockIdx.y;
  int j = blockIdx.x * 256 + threadIdx.x;
  __shared__ float sh_h[Hh];
  sh_h[threadIdx.x] = h_in[b * Hh + threadIdx.x];
  sh_h[256 + threadIdx.x] = h_in[b * Hh + 256 + threadIdx.x];
  __syncthreads();
  float ar = b_hh[j], az = b_hh[Hh + j], an = b_hh[2 * Hh + j];
#pragma unroll 4
  for (int k = 0; k < Hh; k++) {
    float hk = sh_h[k];
    const float* w = WhhT + (size_t)k * G3 + j;
    ar = fmaf(hk, w[0], ar);
    az = fmaf(hk, w[Hh], az);
    an = fmaf(hk, w[2 * Hh], an);
  }
  float xr = gx_t[b * G3 + j];
  float xz = gx_t[b * G3 + Hh + j];
  float xn = gx_t[b * G3 + 2 * Hh + j];
  float r = 1.f / (1.f + __expf(-(xr + ar)));
  float u = 1.f / (1.f + __expf(-(xz + az)));
  float n = tanhf(xn + r * an);
  float hv = sh_h[j];
  float hnew = (1.f - u) * n + u * hv;
  h_out[b * Hh + j] = hnew;
  if (hseq_out) hseq_out[b * Hh + j] = hnew;
}

// ---------------- z = h_last @ fc_enc_W^T + b ----------------
__global__ void k_z(const float* __restrict__ h, const float* __restrict__ W,
                    const float* __restrict__ bias, float* __restrict__ zws,
                    float* __restrict__ zout) {
  int b = blockIdx.x;
  int l = threadIdx.x;  // 128
  __shared__ float hsh[Hh];
  for (int i = threadIdx.x; i < Hh; i += 128) hsh[i] = h[b * Hh + i];
  __syncthreads();
  float acc = bias[l];
#pragma unroll 4
  for (int k = 0; k < Hh; k++) acc = fmaf(hsh[k], W[(size_t)l * Hh + k], acc);
  zws[b * Ll + l] = acc;
  zout[b * Ll + l] = acc;
}

// ---------------- hid0 = tanh(z @ fc_dec_W^T + b) ----------------
__global__ void k_hid0(const float* __restrict__ z, const float* __restrict__ W,
                       const float* __restrict__ bias, float* __restrict__ h0) {
  int b = blockIdx.x;
  int j = threadIdx.x;  // 512
  __shared__ float zsh[Ll];
  if (threadIdx.x < Ll) zsh[threadIdx.x] = z[b * Ll + threadIdx.x];
  __syncthreads();
  float acc = bias[j];
#pragma unroll 4
  for (int l = 0; l < Ll; l++) acc = fmaf(zsh[l], W[(size_t)j * Ll + l], acc);
  h0[b * Hh + j] = tanhf(acc);
}

// ---------------- logits GEMM: hs[2032][512] x dec_fc_W[32000][512]^T ----------------
#define LBM 128
#define LBN 64
#define LBK 16
__global__ void k_logits(const float* __restrict__ A, const float* __restrict__ W,
                         const float* __restrict__ bias, float* __restrict__ out) {
  const int M = 2032;
  int bn = blockIdx.x * LBN;
  int bm = blockIdx.y * LBM;
  __shared__ float As[LBK][LBM + 1];
  __shared__ float Bs[LBK][LBN + 4];
  int tid = threadIdx.x;
  int tx = tid & 15, ty = tid >> 4;
  float acc[8][4];
#pragma unroll
  for (int i = 0; i < 8; i++)
#pragma unroll
    for (int j = 0; j < 4; j++) acc[i][j] = 0.f;

  for (int k0 = 0; k0 < Hh; k0 += LBK) {
#pragma unroll
    for (int p = 0; p < 8; p++) {
      int row = (tid >> 4) + p * 16;
      int m = bm + row;
      As[tid & 15][row] = (m < M) ? A[(size_t)m * Hh + k0 + (tid & 15)] : 0.f;
    }
#pragma unroll
    for (int p = 0; p < 4; p++) {
      int n = (tid >> 4) + p * 16;
      Bs[tid & 15][n] = W[(size_t)(bn + n) * Hh + k0 + (tid & 15)];
    }
    __syncthreads();
#pragma unroll
    for (int k = 0; k < LBK; k++) {
      float a[8], bv[4];
#pragma unroll
      for (int i = 0; i < 8; i++) a[i] = As[k][ty * 8 + i];
#pragma unroll
      for (int j = 0; j < 4; j++) bv[j] = Bs[k][tx * 4 + j];
#pragma unroll
      for (int i = 0; i < 8; i++)
#pragma unroll
        for (int j = 0; j < 4; j++) acc[i][j] = fmaf(a[i], bv[j], acc[i][j]);
    }
    __syncthreads();
  }
#pragma unroll
  for (int i = 0; i < 8; i++) {
    int m = bm + ty * 8 + i;
    if (m >= M) continue;
    int t = m >> 4, b = m & 15;
    float* orow = out + ((size_t)(b * Tt + 1 + t)) * Vv + bn + tx * 4;
#pragma unroll
    for (int j = 0; j < 4; j++) orow[j] = acc[i][j] + bias[bn + tx * 4 + j];
  }
}

extern "C" void kernel_launch(void* const* d_in, const int* in_sizes, int n_in,
                              void* d_out, int out_size, void* d_ws, size_t ws_size,
                              hipStream_t stream) {
  const int* x = (const int*)d_in[0];
  const float* enc_emb = (const float*)d_in[1];
  const float* enc_Wih = (const float*)d_in[2];
  const float* enc_bih = (const float*)d_in[3];
  const float* enc_Whh = (const float*)d_in[4];
  const float* enc_bhh = (const float*)d_in[5];
  const float* fc_enc_W = (const float*)d_in[6];
  const float* fc_enc_b = (const float*)d_in[7];
  const float* fc_dec_W = (const float*)d_in[8];
  const float* fc_dec_b = (const float*)d_in[9];
  const float* dec_emb = (const float*)d_in[10];
  const float* dec_Wih = (const float*)d_in[11];
  const float* dec_bih = (const float*)d_in[12];
  const float* dec_Whh = (const float*)d_in[13];
  const float* dec_bhh = (const float*)d_in[14];
  const float* dec_fcW = (const float*)d_in[15];
  const float* dec_fcb = (const float*)d_in[16];
  float* out = (float*)d_out;

  float* ws = (float*)d_ws;
  float* whhT_e = ws;                      // 512*1536 = 786432
  float* whhT_d = whhT_e + 786432;         // 786432
  float* wihT_e = whhT_d + 786432;         // 256*1536 = 393216
  float* wihT_d = wihT_e + 393216;         // 393216
  float* gx_e = wihT_d + 393216;           // 2048*1536 = 3145728
  float* gx_d = gx_e + 3145728;            // 2032*1536 = 3121152
  float* h_e = gx_d + 3121152;             // 2*16*512 = 16384
  float* hseq = h_e + 16384;               // 2032*512 = 1040384
  float* zbuf = hseq + 1040384;            // 2048
  float* h_d = zbuf + 2048;                // 16384

  // init
  k_zero<<<(Bb * Hh + 255) / 256, 256, 0, stream>>>(h_e, Bb * Hh);
  k_zero_first<<<(Bb * Vv + 255) / 256, 256, 0, stream>>>(out);

  dim3 tb(32, 8);
  k_transpose<<<dim3(512 / 32, 1536 / 32), tb, 0, stream>>>(enc_Whh, whhT_e, 1536, 512);
  k_transpose<<<dim3(512 / 32, 1536 / 32), tb, 0, stream>>>(dec_Whh, whhT_d, 1536, 512);
  k_transpose<<<dim3(256 / 32, 1536 / 32), tb, 0, stream>>>(enc_Wih, wihT_e, 1536, 256);
  k_transpose<<<dim3(256 / 32, 1536 / 32), tb, 0, stream>>>(dec_Wih, wihT_d, 1536, 256);

  // gx precompute (encoder: M = 128*16 = 2048 rows; decoder: M = 127*16 = 2032)
  k_gx<<<dim3(128, 6), 256, 0, stream>>>(x, enc_emb, wihT_e, enc_bih, gx_e);
  k_gx<<<dim3(127, 6), 256, 0, stream>>>(x, dec_emb, wihT_d, dec_bih, gx_d);

  // encoder scan: 128 steps, h ends in h_e[0]
  for (int t = 0; t < 128; t++)
    k_gru_step<<<dim3(2, 16), 256, 0, stream>>>(
        gx_e + (size_t)t * Bb * G3, h_e + (t & 1) * (Bb * Hh),
        h_e + ((t + 1) & 1) * (Bb * Hh), (float*)nullptr, whhT_e, enc_bhh);

  // z (also second output) and hid0
  k_z<<<16, 128, 0, stream>>>(h_e, fc_enc_W, fc_enc_b, zbuf, out + (size_t)Bb * Tt * Vv);
  k_hid0<<<16, 512, 0, stream>>>(zbuf, fc_dec_W, fc_dec_b, h_d);

  // decoder scan: 127 steps, record hseq[t]
  for (int t = 0; t < 127; t++)
    k_gru_step<<<dim3(2, 16), 256, 0, stream>>>(
        gx_d + (size_t)t * Bb * G3, h_d + (t & 1) * (Bb * Hh),
        h_d + ((t + 1) & 1) * (Bb * Hh), hseq + (size_t)t * Bb * Hh, whhT_d, dec_bhh);

  // logits
  k_logits<<<dim3(Vv / LBN, 16), 256, 0, stream>>>(hseq, dec_fcW, dec_fcb, out);
}

// Round 2
// 4035.744 us; speedup vs baseline: 1.9855x; 1.9855x over previous
//
#include <hip/hip_runtime.h>

#define Vv 32000
#define Ee 256
#define Hh 512
#define Ll 128
#define Bb 16
#define Tt 128
#define G3 1536   // 3*H
#define NWG 64    // persistent scan workgroups

__device__ __forceinline__ float sigmoidf_(float x) { return 1.f / (1.f + __expf(-x)); }

// ---------------- zero helper ----------------
__global__ void k_zero(float* __restrict__ p, int n) {
  int i = blockIdx.x * 256 + threadIdx.x;
  if (i < n) p[i] = 0.f;
}

// zero outputs[:, 0, :]
__global__ void k_zero_first(float* __restrict__ out) {
  int idx = blockIdx.x * 256 + threadIdx.x;
  if (idx < Bb * Vv) {
    int b = idx / Vv, v = idx % Vv;
    out[(size_t)b * Tt * Vv + v] = 0.f;
  }
}

// ---------------- transpose: in [R][C] -> out [C][R] ----------------
__global__ void k_transpose(const float* __restrict__ in, float* __restrict__ out,
                            int R, int C) {
  __shared__ float tile[32][33];
  int c = blockIdx.x * 32 + threadIdx.x;
  int r0 = blockIdx.y * 32;
  for (int i = threadIdx.y; i < 32; i += 8)
    tile[i][threadIdx.x] = in[(size_t)(r0 + i) * C + c];
  __syncthreads();
  int r = r0 + threadIdx.x;
  int c0 = blockIdx.x * 32;
  for (int i = threadIdx.y; i < 32; i += 8)
    out[(size_t)(c0 + i) * R + r] = tile[threadIdx.x][i];
}

// ---------------- gx = emb[x] @ W_ih^T + b_ih ----------------
// gx[m][g], m = t*16+b (time-major).  WihT is [Ee][G3].
__global__ void k_gx(const int* __restrict__ x, const float* __restrict__ emb,
                     const float* __restrict__ WihT, const float* __restrict__ b_ih,
                     float* __restrict__ gx) {
  int g = blockIdx.y * 256 + threadIdx.x;
  int mt = blockIdx.x;
  __shared__ float A[16][Ee];
  for (int i = 0; i < 16; i++) {
    int m = mt * 16 + i;
    int t = m >> 4, b = m & 15;
    int tok = x[b * Tt + t];
    A[i][threadIdx.x] = emb[(size_t)tok * Ee + threadIdx.x];
  }
  __syncthreads();
  float acc[16];
  float bg = b_ih[g];
#pragma unroll
  for (int i = 0; i < 16; i++) acc[i] = bg;
#pragma unroll 4
  for (int e = 0; e < Ee; e++) {
    float w = WihT[(size_t)e * G3 + g];
#pragma unroll
    for (int i = 0; i < 16; i++) acc[i] = fmaf(A[i][e], w, acc[i]);
  }
#pragma unroll
  for (int i = 0; i < 16; i++)
    gx[(size_t)(mt * 16 + i) * G3 + g] = acc[i];
}

// ---------------- persistent GRU scan ----------------
// 64 WGs x 256 threads. WG owns 8 h-columns (j0 = wg*8).
// Thread (jloc = tid&7, ks = tid>>3): holds Whh[{r,z,n} rows j][k0..k0+15] in regs.
// Per step: h(global)->LDS, reg FMAs, shfl-reduce over ks, 128 threads finish gates,
// write h_next (double-buffered) + hseq, then all-resident flag barrier.
__global__ void __launch_bounds__(256) k_scan(
    const float* __restrict__ Whh,   // [3H][H] original layout
    const float* __restrict__ bhh,   // [3H]
    const float* __restrict__ gx,    // [nsteps*16][3H]
    float* __restrict__ hbuf,        // [2][16][H]
    float* __restrict__ hseq,        // [nsteps][16][H] or nullptr
    int nsteps, int* __restrict__ flags) {
  __shared__ float h_lds[Bb * Hh];            // 32 KB
  __shared__ float scratch[4][8][3][Bb];      // 6 KB [wave][jloc][gate][b]
  const int tid = threadIdx.x;
  const int wg = blockIdx.x;
  const int jloc = tid & 7;
  const int ks = tid >> 3;    // 0..31 (for tid<128 this is also b)
  const int j0 = wg * 8;
  const int j = j0 + jloc;
  const int k0 = ks * 16;

  // --- load recurrent weights into registers (once) ---
  float wr[16], wz[16], wn[16];
  {
    const float4* R = (const float4*)(Whh + (size_t)j * Hh + k0);
    const float4* Z = (const float4*)(Whh + (size_t)(Hh + j) * Hh + k0);
    const float4* N = (const float4*)(Whh + (size_t)(2 * Hh + j) * Hh + k0);
#pragma unroll
    for (int q = 0; q < 4; ++q) {
      float4 a = R[q]; wr[4*q] = a.x; wr[4*q+1] = a.y; wr[4*q+2] = a.z; wr[4*q+3] = a.w;
      float4 b = Z[q]; wz[4*q] = b.x; wz[4*q+1] = b.y; wz[4*q+2] = b.z; wz[4*q+3] = b.w;
      float4 c = N[q]; wn[4*q] = c.x; wn[4*q+1] = c.y; wn[4*q+2] = c.z; wn[4*q+3] = c.w;
    }
  }
  float bhr = 0.f, bhz = 0.f, bhn = 0.f;
  if (tid < 128) {
    bhr = bhh[j]; bhz = bhh[Hh + j]; bhn = bhh[2 * Hh + j];
  }

  for (int t = 0; t < nsteps; ++t) {
    // stage h -> LDS (coalesced float4)
    {
      const float4* hsrc = (const float4*)(hbuf + (size_t)(t & 1) * (Bb * Hh));
      float4* hl = (float4*)h_lds;
#pragma unroll
      for (int i = 0; i < 8; ++i) hl[tid + 256 * i] = hsrc[tid + 256 * i];
    }
    // early gx loads (consumed at the end; overlap latency with FMA phase)
    float xr = 0.f, xz = 0.f, xn = 0.f;
    if (tid < 128) {
      const float* gp = gx + (size_t)(t * Bb + ks) * G3 + j;
      xr = gp[0]; xz = gp[Hh]; xn = gp[2 * Hh];
    }
    __syncthreads();

    // --- accumulate partial dot products (all from registers / LDS broadcast) ---
    float accR[Bb], accZ[Bb], accN[Bb];
#pragma unroll
    for (int b = 0; b < Bb; ++b) { accR[b] = 0.f; accZ[b] = 0.f; accN[b] = 0.f; }
#pragma unroll
    for (int b = 0; b < Bb; ++b) {
      const float4* hp = (const float4*)(h_lds + b * Hh + k0);
#pragma unroll
      for (int q = 0; q < 4; ++q) {
        float4 hv = hp[q];
        accR[b] = fmaf(wr[4*q+0], hv.x, accR[b]);
        accR[b] = fmaf(wr[4*q+1], hv.y, accR[b]);
        accR[b] = fmaf(wr[4*q+2], hv.z, accR[b]);
        accR[b] = fmaf(wr[4*q+3], hv.w, accR[b]);
        accZ[b] = fmaf(wz[4*q+0], hv.x, accZ[b]);
        accZ[b] = fmaf(wz[4*q+1], hv.y, accZ[b]);
        accZ[b] = fmaf(wz[4*q+2], hv.z, accZ[b]);
        accZ[b] = fmaf(wz[4*q+3], hv.w, accZ[b]);
        accN[b] = fmaf(wn[4*q+0], hv.x, accN[b]);
        accN[b] = fmaf(wn[4*q+1], hv.y, accN[b]);
        accN[b] = fmaf(wn[4*q+2], hv.z, accN[b]);
        accN[b] = fmaf(wn[4*q+3], hv.w, accN[b]);
      }
    }
    // --- reduce over ks within wave (lane bits 3..5 = ks bits 0..2) ---
#pragma unroll
    for (int b = 0; b < Bb; ++b) {
      accR[b] += __shfl_xor(accR[b], 8, 64);
      accR[b] += __shfl_xor(accR[b], 16, 64);
      accR[b] += __shfl_xor(accR[b], 32, 64);
      accZ[b] += __shfl_xor(accZ[b], 8, 64);
      accZ[b] += __shfl_xor(accZ[b], 16, 64);
      accZ[b] += __shfl_xor(accZ[b], 32, 64);
      accN[b] += __shfl_xor(accN[b], 8, 64);
      accN[b] += __shfl_xor(accN[b], 16, 64);
      accN[b] += __shfl_xor(accN[b], 32, 64);
    }
    if ((ks & 7) == 0) {
      const int wv = tid >> 6;
#pragma unroll
      for (int b = 0; b < Bb; ++b) {
        scratch[wv][jloc][0][b] = accR[b];
        scratch[wv][jloc][1][b] = accZ[b];
        scratch[wv][jloc][2][b] = accN[b];
      }
    }
    __syncthreads();

    // --- finish gates, write h_next (+hseq) ---
    float* hdst = hbuf + (size_t)((t + 1) & 1) * (Bb * Hh);
    if (tid < 128) {
      const int b = ks;
      float ar = scratch[0][jloc][0][b] + scratch[1][jloc][0][b] +
                 scratch[2][jloc][0][b] + scratch[3][jloc][0][b] + bhr;
      float az = scratch[0][jloc][1][b] + scratch[1][jloc][1][b] +
                 scratch[2][jloc][1][b] + scratch[3][jloc][1][b] + bhz;
      float an = scratch[0][jloc][2][b] + scratch[1][jloc][2][b] +
                 scratch[2][jloc][2][b] + scratch[3][jloc][2][b] + bhn;
      float r = sigmoidf_(xr + ar);
      float u = sigmoidf_(xz + az);
      float n = tanhf(xn + r * an);
      float hold = h_lds[b * Hh + j];
      float hnew = (1.f - u) * n + u * hold;
      hdst[b * Hh + j] = hnew;
      if (hseq) hseq[((size_t)t * Bb + b) * Hh + j] = hnew;
    }

    // --- device barrier among 64 resident WGs (skip after last step) ---
    if (t < nsteps - 1) {
      __threadfence();
      __syncthreads();
      if (tid == 0)
        __hip_atomic_store(flags + (size_t)wg * 32, t + 1,
                           __ATOMIC_RELEASE, __HIP_MEMORY_SCOPE_AGENT);
      if (tid < NWG) {
        while (__hip_atomic_load(flags + (size_t)tid * 32,
                                 __ATOMIC_ACQUIRE, __HIP_MEMORY_SCOPE_AGENT) < t + 1) {}
      }
      __syncthreads();
    }
  }
}

// ---------------- z = h_last @ fc_enc_W^T + b ----------------
__global__ void k_z(const float* __restrict__ h, const float* __restrict__ W,
                    const float* __restrict__ bias, float* __restrict__ zws,
                    float* __restrict__ zout) {
  int b = blockIdx.x;
  int l = threadIdx.x;  // 128
  __shared__ float hsh[Hh];
  for (int i = threadIdx.x; i < Hh; i += 128) hsh[i] = h[b * Hh + i];
  __syncthreads();
  float acc = bias[l];
#pragma unroll 4
  for (int k = 0; k < Hh; k++) acc = fmaf(hsh[k], W[(size_t)l * Hh + k], acc);
  zws[b * Ll + l] = acc;
  zout[b * Ll + l] = acc;
}

// ---------------- hid0 = tanh(z @ fc_dec_W^T + b) ----------------
__global__ void k_hid0(const float* __restrict__ z, const float* __restrict__ W,
                       const float* __restrict__ bias, float* __restrict__ h0) {
  int b = blockIdx.x;
  int j = threadIdx.x;  // 512
  __shared__ float zsh[Ll];
  if (threadIdx.x < Ll) zsh[threadIdx.x] = z[b * Ll + threadIdx.x];
  __syncthreads();
  float acc = bias[j];
#pragma unroll 4
  for (int l = 0; l < Ll; l++) acc = fmaf(zsh[l], W[(size_t)j * Ll + l], acc);
  h0[b * Hh + j] = tanhf(acc);
}

// ---------------- logits GEMM: hs[2032][512] x dec_fc_W[32000][512]^T ----------------
#define LBM 128
#define LBN 64
#define LBK 16
__global__ void k_logits(const float* __restrict__ A, const float* __restrict__ W,
                         const float* __restrict__ bias, float* __restrict__ out) {
  const int M = 2032;
  int bn = blockIdx.x * LBN;
  int bm = blockIdx.y * LBM;
  __shared__ float As[LBK][LBM + 1];
  __shared__ float Bs[LBK][LBN + 4];
  int tid = threadIdx.x;
  int tx = tid & 15, ty = tid >> 4;
  float acc[8][4];
#pragma unroll
  for (int i = 0; i < 8; i++)
#pragma unroll
    for (int j = 0; j < 4; j++) acc[i][j] = 0.f;

  for (int k0 = 0; k0 < Hh; k0 += LBK) {
#pragma unroll
    for (int p = 0; p < 8; p++) {
      int row = (tid >> 4) + p * 16;
      int m = bm + row;
      As[tid & 15][row] = (m < M) ? A[(size_t)m * Hh + k0 + (tid & 15)] : 0.f;
    }
#pragma unroll
    for (int p = 0; p < 4; p++) {
      int n = (tid >> 4) + p * 16;
      Bs[tid & 15][n] = W[(size_t)(bn + n) * Hh + k0 + (tid & 15)];
    }
    __syncthreads();
#pragma unroll
    for (int k = 0; k < LBK; k++) {
      float a[8], bv[4];
#pragma unroll
      for (int i = 0; i < 8; i++) a[i] = As[k][ty * 8 + i];
#pragma unroll
      for (int j = 0; j < 4; j++) bv[j] = Bs[k][tx * 4 + j];
#pragma unroll
      for (int i = 0; i < 8; i++)
#pragma unroll
        for (int j = 0; j < 4; j++) acc[i][j] = fmaf(a[i], bv[j], acc[i][j]);
    }
    __syncthreads();
  }
#pragma unroll
  for (int i = 0; i < 8; i++) {
    int m = bm + ty * 8 + i;
    if (m >= M) continue;
    int t = m >> 4, b = m & 15;
    float* orow = out + ((size_t)(b * Tt + 1 + t)) * Vv + bn + tx * 4;
#pragma unroll
    for (int j = 0; j < 4; j++) orow[j] = acc[i][j] + bias[bn + tx * 4 + j];
  }
}

extern "C" void kernel_launch(void* const* d_in, const int* in_sizes, int n_in,
                              void* d_out, int out_size, void* d_ws, size_t ws_size,
                              hipStream_t stream) {
  const int* x = (const int*)d_in[0];
  const float* enc_emb = (const float*)d_in[1];
  const float* enc_Wih = (const float*)d_in[2];
  const float* enc_bih = (const float*)d_in[3];
  const float* enc_Whh = (const float*)d_in[4];
  const float* enc_bhh = (const float*)d_in[5];
  const float* fc_enc_W = (const float*)d_in[6];
  const float* fc_enc_b = (const float*)d_in[7];
  const float* fc_dec_W = (const float*)d_in[8];
  const float* fc_dec_b = (const float*)d_in[9];
  const float* dec_emb = (const float*)d_in[10];
  const float* dec_Wih = (const float*)d_in[11];
  const float* dec_bih = (const float*)d_in[12];
  const float* dec_Whh = (const float*)d_in[13];
  const float* dec_bhh = (const float*)d_in[14];
  const float* dec_fcW = (const float*)d_in[15];
  const float* dec_fcb = (const float*)d_in[16];
  float* out = (float*)d_out;

  float* ws = (float*)d_ws;
  float* wihT_e = ws;                      // 256*1536 = 393216
  float* wihT_d = wihT_e + 393216;         // 393216
  float* gx_e = wihT_d + 393216;           // 2048*1536 = 3145728
  float* gx_d = gx_e + 3145728;            // 2032*1536 = 3121152
  float* hbuf = gx_d + 3121152;            // 2*16*512 = 16384
  float* hseq = hbuf + 16384;              // 2032*512 = 1040384
  float* zbuf = hseq + 1040384;            // 2048
  int* flags_e = (int*)(zbuf + 2048);      // 64*32 ints
  int* flags_d = flags_e + 64 * 32;        // 64*32 ints

  // init: barrier flags, h0 = 0, outputs[:,0,:] = 0
  hipMemsetAsync(flags_e, 0, 2 * 64 * 32 * sizeof(int), stream);
  k_zero<<<(Bb * Hh + 255) / 256, 256, 0, stream>>>(hbuf, Bb * Hh);
  k_zero_first<<<(Bb * Vv + 255) / 256, 256, 0, stream>>>(out);

  // W_ih transposes for k_gx
  dim3 tb(32, 8);
  k_transpose<<<dim3(256 / 32, 1536 / 32), tb, 0, stream>>>(enc_Wih, wihT_e, 1536, 256);
  k_transpose<<<dim3(256 / 32, 1536 / 32), tb, 0, stream>>>(dec_Wih, wihT_d, 1536, 256);

  // gx precompute (encoder: 2048 rows; decoder: 2032 rows)
  k_gx<<<dim3(128, 6), 256, 0, stream>>>(x, enc_emb, wihT_e, enc_bih, gx_e);
  k_gx<<<dim3(127, 6), 256, 0, stream>>>(x, dec_emb, wihT_d, dec_bih, gx_d);

  // encoder scan: 128 steps; h ends in hbuf[0]
  k_scan<<<NWG, 256, 0, stream>>>(enc_Whh, enc_bhh, gx_e, hbuf, (float*)nullptr,
                                  128, flags_e);

  // z (also second output) and hid0 (decoder initial h -> hbuf[0])
  k_z<<<16, 128, 0, stream>>>(hbuf, fc_enc_W, fc_enc_b, zbuf, out + (size_t)Bb * Tt * Vv);
  k_hid0<<<16, 512, 0, stream>>>(zbuf, fc_dec_W, fc_dec_b, hbuf);

  // decoder scan: 127 steps, record hseq
  k_scan<<<NWG, 256, 0, stream>>>(dec_Whh, dec_bhh, gx_d, hbuf, hseq, 127, flags_d);

  // logits
  k_logits<<<dim3(Vv / LBN, 16), 256, 0, stream>>>(hseq, dec_fcW, dec_fcb, out);
}

// Round 3
// 3172.280 us; speedup vs baseline: 2.5260x; 1.2722x over previous
//
#include <hip/hip_runtime.h>

#define Vv 32000
#define Ee 256
#define Hh 512
#define Ll 128
#define Bb 16
#define Tt 128
#define G3 1536   // 3*H
#define NWG 64    // persistent scan workgroups

typedef __attribute__((ext_vector_type(8))) short short8;
typedef __attribute__((ext_vector_type(4))) float f32x4;

__device__ __forceinline__ float sigmoidf_(float x) { return 1.f / (1.f + __expf(-x)); }

// f32 -> bf16 round-to-nearest-even
__device__ __forceinline__ unsigned short f2bf(float f) {
  unsigned int u = __float_as_uint(f);
  u = (u + 0x7fffu + ((u >> 16) & 1u)) >> 16;
  return (unsigned short)u;
}

// ---------------- zero helper ----------------
__global__ void k_zero(float* __restrict__ p, int n) {
  int i = blockIdx.x * 256 + threadIdx.x;
  if (i < n) p[i] = 0.f;
}

// zero outputs[:, 0, :]
__global__ void k_zero_first(float* __restrict__ out) {
  int idx = blockIdx.x * 256 + threadIdx.x;
  if (idx < Bb * Vv) {
    int b = idx / Vv, v = idx % Vv;
    out[(size_t)b * Tt * Vv + v] = 0.f;
  }
}

// ---------------- f32 -> bf16 bulk convert (float4 granularity) ----------------
__global__ void k_cvt_bf16(const float* __restrict__ in, unsigned short* __restrict__ out,
                           int n4) {
  int i = blockIdx.x * 256 + threadIdx.x;
  if (i < n4) {
    float4 v = ((const float4*)in)[i];
    ushort4 o;
    o.x = f2bf(v.x); o.y = f2bf(v.y); o.z = f2bf(v.z); o.w = f2bf(v.w);
    ((ushort4*)out)[i] = o;
  }
}

// ---------------- transpose: in [R][C] -> out [C][R] ----------------
__global__ void k_transpose(const float* __restrict__ in, float* __restrict__ out,
                            int R, int C) {
  __shared__ float tile[32][33];
  int c = blockIdx.x * 32 + threadIdx.x;
  int r0 = blockIdx.y * 32;
  for (int i = threadIdx.y; i < 32; i += 8)
    tile[i][threadIdx.x] = in[(size_t)(r0 + i) * C + c];
  __syncthreads();
  int r = r0 + threadIdx.x;
  int c0 = blockIdx.x * 32;
  for (int i = threadIdx.y; i < 32; i += 8)
    out[(size_t)(c0 + i) * R + r] = tile[threadIdx.x][i];
}

// ---------------- gx = emb[x] @ W_ih^T + b_ih ----------------
__global__ void k_gx(const int* __restrict__ x, const float* __restrict__ emb,
                     const float* __restrict__ WihT, const float* __restrict__ b_ih,
                     float* __restrict__ gx) {
  int g = blockIdx.y * 256 + threadIdx.x;
  int mt = blockIdx.x;
  __shared__ float A[16][Ee];
  for (int i = 0; i < 16; i++) {
    int m = mt * 16 + i;
    int t = m >> 4, b = m & 15;
    int tok = x[b * Tt + t];
    A[i][threadIdx.x] = emb[(size_t)tok * Ee + threadIdx.x];
  }
  __syncthreads();
  float acc[16];
  float bg = b_ih[g];
#pragma unroll
  for (int i = 0; i < 16; i++) acc[i] = bg;
#pragma unroll 4
  for (int e = 0; e < Ee; e++) {
    float w = WihT[(size_t)e * G3 + g];
#pragma unroll
    for (int i = 0; i < 16; i++) acc[i] = fmaf(A[i][e], w, acc[i]);
  }
#pragma unroll
  for (int i = 0; i < 16; i++)
    gx[(size_t)(mt * 16 + i) * G3 + g] = acc[i];
}

// ---------------- persistent GRU scan (relaxed-spin barrier) ----------------
__global__ void __launch_bounds__(256) k_scan(
    const float* __restrict__ Whh,   // [3H][H]
    const float* __restrict__ bhh,   // [3H]
    const float* __restrict__ gx,    // [nsteps*16][3H]
    float* __restrict__ hbuf,        // [2][16][H]
    unsigned short* __restrict__ hseq,  // [nsteps][16][H] bf16, or nullptr
    int nsteps, int* __restrict__ flags) {
  __shared__ float h_lds[Bb * Hh];            // 32 KB
  __shared__ float scratch[4][8][3][Bb];      // 6 KB
  const int tid = threadIdx.x;
  const int wg = blockIdx.x;
  const int jloc = tid & 7;
  const int ks = tid >> 3;    // 0..31
  const int j = wg * 8 + jloc;
  const int k0 = ks * 16;

  // load recurrent weights into registers (once)
  float wr[16], wz[16], wn[16];
  {
    const float4* R = (const float4*)(Whh + (size_t)j * Hh + k0);
    const float4* Z = (const float4*)(Whh + (size_t)(Hh + j) * Hh + k0);
    const float4* N = (const float4*)(Whh + (size_t)(2 * Hh + j) * Hh + k0);
#pragma unroll
    for (int q = 0; q < 4; ++q) {
      float4 a = R[q]; wr[4*q] = a.x; wr[4*q+1] = a.y; wr[4*q+2] = a.z; wr[4*q+3] = a.w;
      float4 b = Z[q]; wz[4*q] = b.x; wz[4*q+1] = b.y; wz[4*q+2] = b.z; wz[4*q+3] = b.w;
      float4 c = N[q]; wn[4*q] = c.x; wn[4*q+1] = c.y; wn[4*q+2] = c.z; wn[4*q+3] = c.w;
    }
  }
  float bhr = 0.f, bhz = 0.f, bhn = 0.f;
  if (tid < 128) { bhr = bhh[j]; bhz = bhh[Hh + j]; bhn = bhh[2 * Hh + j]; }

  for (int t = 0; t < nsteps; ++t) {
    // stage h -> LDS
    {
      const float4* hsrc = (const float4*)(hbuf + (size_t)(t & 1) * (Bb * Hh));
      float4* hl = (float4*)h_lds;
#pragma unroll
      for (int i = 0; i < 8; ++i) hl[tid + 256 * i] = hsrc[tid + 256 * i];
    }
    float xr = 0.f, xz = 0.f, xn = 0.f;
    if (tid < 128) {
      const float* gp = gx + (size_t)(t * Bb + ks) * G3 + j;
      xr = gp[0]; xz = gp[Hh]; xn = gp[2 * Hh];
    }
    __syncthreads();

    float accR[Bb], accZ[Bb], accN[Bb];
#pragma unroll
    for (int b = 0; b < Bb; ++b) { accR[b] = 0.f; accZ[b] = 0.f; accN[b] = 0.f; }
#pragma unroll
    for (int b = 0; b < Bb; ++b) {
      const float4* hp = (const float4*)(h_lds + b * Hh + k0);
#pragma unroll
      for (int q = 0; q < 4; ++q) {
        float4 hv = hp[q];
        accR[b] = fmaf(wr[4*q+0], hv.x, accR[b]);
        accR[b] = fmaf(wr[4*q+1], hv.y, accR[b]);
        accR[b] = fmaf(wr[4*q+2], hv.z, accR[b]);
        accR[b] = fmaf(wr[4*q+3], hv.w, accR[b]);
        accZ[b] = fmaf(wz[4*q+0], hv.x, accZ[b]);
        accZ[b] = fmaf(wz[4*q+1], hv.y, accZ[b]);
        accZ[b] = fmaf(wz[4*q+2], hv.z, accZ[b]);
        accZ[b] = fmaf(wz[4*q+3], hv.w, accZ[b]);
        accN[b] = fmaf(wn[4*q+0], hv.x, accN[b]);
        accN[b] = fmaf(wn[4*q+1], hv.y, accN[b]);
        accN[b] = fmaf(wn[4*q+2], hv.z, accN[b]);
        accN[b] = fmaf(wn[4*q+3], hv.w, accN[b]);
      }
    }
#pragma unroll
    for (int b = 0; b < Bb; ++b) {
      accR[b] += __shfl_xor(accR[b], 8, 64);
      accR[b] += __shfl_xor(accR[b], 16, 64);
      accR[b] += __shfl_xor(accR[b], 32, 64);
      accZ[b] += __shfl_xor(accZ[b], 8, 64);
      accZ[b] += __shfl_xor(accZ[b], 16, 64);
      accZ[b] += __shfl_xor(accZ[b], 32, 64);
      accN[b] += __shfl_xor(accN[b], 8, 64);
      accN[b] += __shfl_xor(accN[b], 16, 64);
      accN[b] += __shfl_xor(accN[b], 32, 64);
    }
    if ((ks & 7) == 0) {
      const int wv = tid >> 6;
#pragma unroll
      for (int b = 0; b < Bb; ++b) {
        scratch[wv][jloc][0][b] = accR[b];
        scratch[wv][jloc][1][b] = accZ[b];
        scratch[wv][jloc][2][b] = accN[b];
      }
    }
    __syncthreads();

    float* hdst = hbuf + (size_t)((t + 1) & 1) * (Bb * Hh);
    if (tid < 128) {
      const int b = ks;
      float ar = scratch[0][jloc][0][b] + scratch[1][jloc][0][b] +
                 scratch[2][jloc][0][b] + scratch[3][jloc][0][b] + bhr;
      float az = scratch[0][jloc][1][b] + scratch[1][jloc][1][b] +
                 scratch[2][jloc][1][b] + scratch[3][jloc][1][b] + bhz;
      float an = scratch[0][jloc][2][b] + scratch[1][jloc][2][b] +
                 scratch[2][jloc][2][b] + scratch[3][jloc][2][b] + bhn;
      float r = sigmoidf_(xr + ar);
      float u = sigmoidf_(xz + az);
      float n = tanhf(xn + r * an);
      float hold = h_lds[b * Hh + j];
      float hnew = (1.f - u) * n + u * hold;
      hdst[b * Hh + j] = hnew;
      if (hseq) hseq[((size_t)t * Bb + b) * Hh + j] = f2bf(hnew);
    }

    // ---- fast device barrier: writer-fence -> relaxed flag -> relaxed spin -> reader-fence
    if (t < nsteps - 1) {
      if (tid < 128) __threadfence();   // drain h/hseq stores (writer waves only)
      __syncthreads();
      if (tid == 0)
        __hip_atomic_store(&flags[wg], t + 1, __ATOMIC_RELAXED, __HIP_MEMORY_SCOPE_AGENT);
      if (tid < NWG) {
        while (__hip_atomic_load(&flags[tid], __ATOMIC_RELAXED,
                                 __HIP_MEMORY_SCOPE_AGENT) < t + 1) {}
        __threadfence();                // single reader-side invalidate (wave 0)
      }
      __syncthreads();
    }
  }
}

// ---------------- z = h_last @ fc_enc_W^T + b ----------------
__global__ void k_z(const float* __restrict__ h, const float* __restrict__ W,
                    const float* __restrict__ bias, float* __restrict__ zws,
                    float* __restrict__ zout) {
  int b = blockIdx.x;
  int l = threadIdx.x;  // 128
  __shared__ float hsh[Hh];
  for (int i = threadIdx.x; i < Hh; i += 128) hsh[i] = h[b * Hh + i];
  __syncthreads();
  float acc = bias[l];
#pragma unroll 4
  for (int k = 0; k < Hh; k++) acc = fmaf(hsh[k], W[(size_t)l * Hh + k], acc);
  zws[b * Ll + l] = acc;
  zout[b * Ll + l] = acc;
}

// ---------------- hid0 = tanh(z @ fc_dec_W^T + b) ----------------
__global__ void k_hid0(const float* __restrict__ z, const float* __restrict__ W,
                       const float* __restrict__ bias, float* __restrict__ h0) {
  int b = blockIdx.x;
  int j = threadIdx.x;  // 512
  __shared__ float zsh[Ll];
  if (threadIdx.x < Ll) zsh[threadIdx.x] = z[b * Ll + threadIdx.x];
  __syncthreads();
  float acc = bias[j];
#pragma unroll 4
  for (int l = 0; l < Ll; l++) acc = fmaf(zsh[l], W[(size_t)j * Ll + l], acc);
  h0[b * Hh + j] = tanhf(acc);
}

// ---------------- logits via MFMA bf16 ----------------
// C[m][n] = hs[m][k] * W[n][k] ; A-frag: row=lane&15, k=8*(lane>>4)+e
// B-frag: col=lane&15, k=8*(lane>>4)+e ; D: col=lane&15, row=(lane>>4)*4+reg
template <bool BF16W>
__global__ void __launch_bounds__(256) k_logits_mfma(
    const unsigned short* __restrict__ Abf,  // [2048][512] bf16 (padded rows)
    const unsigned short* __restrict__ Wbf,  // [32000][512] bf16 (if BF16W)
    const float* __restrict__ Wf,            // [32000][512] f32 (fallback)
    const float* __restrict__ bias, float* __restrict__ out) {
  const int tid = threadIdx.x;
  const int wid = tid >> 6, lane = tid & 63;
  const int ln = lane & 15, hi = lane >> 4;
  const int n0 = blockIdx.x * 64;
  const int m0 = blockIdx.y * 256 + wid * 64;
  f32x4 acc[4][4];
#pragma unroll
  for (int mi = 0; mi < 4; ++mi)
#pragma unroll
    for (int ni = 0; ni < 4; ++ni) acc[mi][ni] = (f32x4)0.f;

  const unsigned short* ap = Abf + (size_t)(m0 + ln) * Hh + hi * 8;
  const unsigned short* bp16 = Wbf + (size_t)(n0 + ln) * Hh + hi * 8;
  const float* bp32 = Wf + (size_t)(n0 + ln) * Hh + hi * 8;

  for (int kt = 0; kt < 16; ++kt) {
    short8 a[4], b[4];
#pragma unroll
    for (int mi = 0; mi < 4; ++mi)
      a[mi] = *(const short8*)(ap + (size_t)mi * 16 * Hh + kt * 32);
#pragma unroll
    for (int ni = 0; ni < 4; ++ni) {
      if (BF16W) {
        b[ni] = *(const short8*)(bp16 + (size_t)ni * 16 * Hh + kt * 32);
      } else {
        const float* q = bp32 + (size_t)ni * 16 * Hh + kt * 32;
        short8 tv;
#pragma unroll
        for (int e = 0; e < 8; ++e) tv[e] = (short)f2bf(q[e]);
        b[ni] = tv;
      }
    }
#pragma unroll
    for (int mi = 0; mi < 4; ++mi)
#pragma unroll
      for (int ni = 0; ni < 4; ++ni)
        acc[mi][ni] = __builtin_amdgcn_mfma_f32_16x16x32_bf16(a[mi], b[ni], acc[mi][ni], 0, 0, 0);
  }

#pragma unroll
  for (int ni = 0; ni < 4; ++ni) {
    int n = n0 + ni * 16 + ln;
    float bv = bias[n];
#pragma unroll
    for (int mi = 0; mi < 4; ++mi) {
      int mbase = m0 + mi * 16 + hi * 4;
#pragma unroll
      for (int r = 0; r < 4; ++r) {
        int m = mbase + r;
        if (m < 2032) {
          int t = m >> 4, bb = m & 15;
          out[((size_t)(bb * Tt + 1 + t)) * Vv + n] = acc[mi][ni][r] + bv;
        }
      }
    }
  }
}

extern "C" void kernel_launch(void* const* d_in, const int* in_sizes, int n_in,
                              void* d_out, int out_size, void* d_ws, size_t ws_size,
                              hipStream_t stream) {
  const int* x = (const int*)d_in[0];
  const float* enc_emb = (const float*)d_in[1];
  const float* enc_Wih = (const float*)d_in[2];
  const float* enc_bih = (const float*)d_in[3];
  const float* enc_Whh = (const float*)d_in[4];
  const float* enc_bhh = (const float*)d_in[5];
  const float* fc_enc_W = (const float*)d_in[6];
  const float* fc_enc_b = (const float*)d_in[7];
  const float* fc_dec_W = (const float*)d_in[8];
  const float* fc_dec_b = (const float*)d_in[9];
  const float* dec_emb = (const float*)d_in[10];
  const float* dec_Wih = (const float*)d_in[11];
  const float* dec_bih = (const float*)d_in[12];
  const float* dec_Whh = (const float*)d_in[13];
  const float* dec_bhh = (const float*)d_in[14];
  const float* dec_fcW = (const float*)d_in[15];
  const float* dec_fcb = (const float*)d_in[16];
  float* out = (float*)d_out;

  float* ws = (float*)d_ws;
  size_t off = 0;
  float* wihT_e = ws + off; off += 393216;
  float* wihT_d = ws + off; off += 393216;
  float* gx_e = ws + off; off += 3145728;
  float* gx_d = ws + off; off += 3121152;
  float* hbuf = ws + off; off += 16384;
  float* zbuf = ws + off; off += 2048;
  int* flags_e = (int*)(ws + off); off += 512;   // enc at +0, dec at +128 ints
  int* flags_d = flags_e + 128;
  unsigned short* hseq_bf = (unsigned short*)(ws + off); off += 524288;  // 2048x512 bf16
  size_t wbf_elems = (size_t)Vv * Hh;            // 16.384M ushort = 8.192M floats
  bool use_wbf = (off + wbf_elems / 2) * sizeof(float) <= ws_size;
  unsigned short* wbf = (unsigned short*)(ws + off);

  // init: barrier flags, h0 = 0, outputs[:,0,:] = 0
  hipMemsetAsync(flags_e, 0, 512 * sizeof(int), stream);
  k_zero<<<(Bb * Hh + 255) / 256, 256, 0, stream>>>(hbuf, Bb * Hh);
  k_zero_first<<<(Bb * Vv + 255) / 256, 256, 0, stream>>>(out);

  // dec_fc_W -> bf16 (if workspace allows)
  if (use_wbf)
    k_cvt_bf16<<<(int)((wbf_elems / 4 + 255) / 256), 256, 0, stream>>>(
        dec_fcW, wbf, (int)(wbf_elems / 4));

  // W_ih transposes for k_gx
  dim3 tb(32, 8);
  k_transpose<<<dim3(256 / 32, 1536 / 32), tb, 0, stream>>>(enc_Wih, wihT_e, 1536, 256);
  k_transpose<<<dim3(256 / 32, 1536 / 32), tb, 0, stream>>>(dec_Wih, wihT_d, 1536, 256);

  // gx precompute
  k_gx<<<dim3(128, 6), 256, 0, stream>>>(x, enc_emb, wihT_e, enc_bih, gx_e);
  k_gx<<<dim3(127, 6), 256, 0, stream>>>(x, dec_emb, wihT_d, dec_bih, gx_d);

  // encoder scan: 128 steps; h ends in hbuf[0]
  k_scan<<<NWG, 256, 0, stream>>>(enc_Whh, enc_bhh, gx_e, hbuf,
                                  (unsigned short*)nullptr, 128, flags_e);

  // z (second output) and hid0
  k_z<<<16, 128, 0, stream>>>(hbuf, fc_enc_W, fc_enc_b, zbuf, out + (size_t)Bb * Tt * Vv);
  k_hid0<<<16, 512, 0, stream>>>(zbuf, fc_dec_W, fc_dec_b, hbuf);

  // decoder scan: 127 steps, record hseq (bf16)
  k_scan<<<NWG, 256, 0, stream>>>(dec_Whh, dec_bhh, gx_d, hbuf, hseq_bf, 127, flags_d);

  // logits via MFMA
  if (use_wbf)
    k_logits_mfma<true><<<dim3(Vv / 64, 8), 256, 0, stream>>>(hseq_bf, wbf, dec_fcW,
                                                              dec_fcb, out);
  else
    k_logits_mfma<false><<<dim3(Vv / 64, 8), 256, 0, stream>>>(hseq_bf, (unsigned short*)nullptr,
                                                               dec_fcW, dec_fcb, out);
}